// Round 3
// baseline (84.837 us; speedup 1.0000x reference)
//
#include <hip/hip_runtime.h>
#include <hip/hip_bf16.h>

// Quantum circuit: 4 qubits, batch 131072.
//
// angles[b][q] = sum_{g<16} x[b][g*4+q]        (RY fusion; RY(a)RY(b)=RY(a+b))
// psi = kron_q [cos(a_q/2), sin(a_q/2)]        (REAL product state)
// out[b][q] = <psi| U^dag Z_q U |psi>,  U = fixed 2-layer unitary(params).
//
// Pauli-basis reduction: for a real product state, <Y-containing strings> = 0,
// <I>=1, <X_q>=sin a_q, <Z_q>=cos a_q.  Hence
//     out_q = sum_{t in 3^4} C_q[t] * prod_q f_q(t_q),  f_q in {1, cos a_q, sin a_q}.
// qc_setup builds C (4 x 81 floats, 1296 B) in d_ws; qc_main is then just
// 16 float4 loads + 4 hw sincos + ~70 muls + 324 fma per batch element.

__global__ void qc_setup(const float* __restrict__ params, float4* __restrict__ C4)
{
    // one block, 256 threads.
    __shared__ float  Ur[16][16];   // [k][col]
    __shared__ float  Ui[16][16];
    __shared__ float4 Mlds[256];    // M_q[i][j] for q=0..3 in lanes (NOT doubled)
    const int tid = threadIdx.x;

    // --- phase 1: threads 0..15 each simulate one basis column of U ---
    if (tid < 16) {
        const int col = tid;
        float ur[16], ui[16];
        #pragma unroll
        for (int k = 0; k < 16; ++k) { ur[k] = (k == col) ? 1.f : 0.f; ui[k] = 0.f; }

        #pragma unroll
        for (int l = 0; l < 2; ++l) {
            #pragma unroll
            for (int q = 0; q < 4; ++q) {
                const float phi = params[l*12 + q*3 + 0];
                const float th  = params[l*12 + q*3 + 1];
                const float om  = params[l*12 + q*3 + 2];
                const float ct = cosf(0.5f*th), st = sinf(0.5f*th);
                const float ap = 0.5f*(phi + om), am = 0.5f*(phi - om);
                const float cap = cosf(ap), sap = sinf(ap);
                const float cam = cosf(am), sam = sinf(am);
                // U00 = ct e^{-i ap}; U01 = -st e^{+i am}; U10 = st e^{-i am}; U11 = ct e^{+i ap}
                const float u00r =  ct*cap, u00i = -ct*sap;
                const float u01r = -st*cam, u01i = -st*sam;
                const float u10r =  st*cam, u10i = -st*sam;
                const float u11r =  ct*cap, u11i =  ct*sap;
                const int bit = 1 << (3 - q);
                #pragma unroll
                for (int k = 0; k < 16; ++k) {
                    if (k & bit) continue;
                    const int k1 = k | bit;
                    const float arr = ur[k],  aii = ui[k];
                    const float brr = ur[k1], bii = ui[k1];
                    ur[k]  = u00r*arr - u00i*aii + u01r*brr - u01i*bii;
                    ui[k]  = u00r*aii + u00i*arr + u01r*bii + u01i*brr;
                    ur[k1] = u10r*arr - u10i*aii + u11r*brr - u11i*bii;
                    ui[k1] = u10r*aii + u10i*arr + u11r*bii + u11i*brr;
                }
            }
            // CNOT ring (0,1),(1,2),(2,3),(3,0); qubit q lives in bit (3-q)
            const int cs[4] = {0,1,2,3}, ts[4] = {1,2,3,0};
            #pragma unroll
            for (int e = 0; e < 4; ++e) {
                const int cb = 3 - cs[e], tb = 3 - ts[e];
                float nr[16], ni[16];
                #pragma unroll
                for (int k = 0; k < 16; ++k) {
                    const int src = ((k >> cb) & 1) ? (k ^ (1 << tb)) : k;
                    nr[k] = ur[src]; ni[k] = ui[src];
                }
                #pragma unroll
                for (int k = 0; k < 16; ++k) { ur[k] = nr[k]; ui[k] = ni[k]; }
            }
        }
        #pragma unroll
        for (int k = 0; k < 16; ++k) { Ur[k][col] = ur[k]; Ui[k][col] = ui[k]; }
    }
    __syncthreads();

    // --- phase 2: thread (i,j) computes M_q[i][j] = sum_k z_q(k)(Ur[k][i]Ur[k][j]+Ui..) ---
    {
        const int i = tid >> 4, j = tid & 15;
        float m0 = 0.f, m1 = 0.f, m2 = 0.f, m3 = 0.f;
        #pragma unroll
        for (int k = 0; k < 16; ++k) {
            const float dot = Ur[k][i]*Ur[k][j] + Ui[k][i]*Ui[k][j];
            m0 += ((k >> 3) & 1) ? -dot : dot;
            m1 += ((k >> 2) & 1) ? -dot : dot;
            m2 += ((k >> 1) & 1) ? -dot : dot;
            m3 += ( k       & 1) ? -dot : dot;
        }
        float4 o; o.x = m0; o.y = m1; o.z = m2; o.w = m3;
        Mlds[tid] = o;
    }
    __syncthreads();

    // --- phase 3: threads 0..80 gather monomial coefficients ---
    // t = d0 + 3*d1 + 9*d2 + 27*d3, d_q in {0:I, 1:cos(Z), 2:sin(X)} for qubit q.
    // Per qubit: d=0 -> (bi,bj) in {(0,0),(1,1)} w=+1/2 each
    //            d=1 -> (0,0) w=+1/2, (1,1) w=-1/2
    //            d=2 -> (0,1) and (1,0), w=+1/2 each
    if (tid < 81) {
        int d[4]; int tt = tid;
        d[0] = tt % 3; tt /= 3; d[1] = tt % 3; tt /= 3; d[2] = tt % 3; d[3] = tt / 3;
        float ax = 0.f, ay = 0.f, az = 0.f, aw = 0.f;
        #pragma unroll
        for (int combo = 0; combo < 16; ++combo) {
            int i = 0, j = 0; float w = 1.f;
            #pragma unroll
            for (int q = 0; q < 4; ++q) {
                const int o = (combo >> q) & 1;
                int bi, bj; float wq;
                if (d[q] == 2)      { bi = o; bj = 1 - o; wq = 0.5f; }
                else if (d[q] == 1) { bi = o; bj = o;     wq = o ? -0.5f : 0.5f; }
                else                { bi = o; bj = o;     wq = 0.5f; }
                i |= bi << (3 - q); j |= bj << (3 - q);
                w *= wq;
            }
            const float4 m = Mlds[i*16 + j];
            ax = fmaf(w, m.x, ax);
            ay = fmaf(w, m.y, ay);
            az = fmaf(w, m.z, az);
            aw = fmaf(w, m.w, aw);
        }
        float4 c; c.x = ax; c.y = ay; c.z = az; c.w = aw;
        C4[tid] = c;
    }
}

__global__ __launch_bounds__(256) void qc_main(const float4* __restrict__ x4,
                                               const float4* __restrict__ C4,
                                               float4* __restrict__ out4)
{
    const int b = blockIdx.x * 256 + threadIdx.x;
    const float4* row = x4 + ((size_t)b << 4);

    // angle sums (x row is 64 floats = 16 float4; lanes = qubits)
    float a0 = 0.f, a1 = 0.f, a2 = 0.f, a3 = 0.f;
    #pragma unroll
    for (int j = 0; j < 16; ++j) {
        const float4 v = row[j];
        a0 += v.x; a1 += v.y; a2 += v.z; a3 += v.w;
    }

    // FULL-angle hw sincos: <X_q> = sin a_q, <Z_q> = cos a_q
    float c0,s0,c1,s1,c2,s2,c3,s3;
    __sincosf(a0, &s0, &c0);
    __sincosf(a1, &s1, &c1);
    __sincosf(a2, &s2, &c2);
    __sincosf(a3, &s3, &c3);

    const float g0[3] = {1.f, c0, s0};
    const float g1[3] = {1.f, c1, s1};
    const float g2[3] = {1.f, c2, s2};
    const float g3[3] = {1.f, c3, s3};
    float P01[9], P23[9];
    #pragma unroll
    for (int e1 = 0; e1 < 3; ++e1)
        #pragma unroll
        for (int e0 = 0; e0 < 3; ++e0) {
            P01[e0 + 3*e1] = g0[e0] * g1[e1];   // 1.f* folds away
            P23[e0 + 3*e1] = g2[e0] * g3[e1];
        }

    // out_q = sum_t C_q[t] * P01[t%9] * P23[t/9]; C is wave-uniform -> s_load
    float ax = 0.f, ay = 0.f, az = 0.f, aw = 0.f;
    #pragma unroll
    for (int t = 0; t < 81; ++t) {
        const float T = P01[t % 9] * P23[t / 9];
        const float4 m = C4[t];
        ax = fmaf(T, m.x, ax);
        ay = fmaf(T, m.y, ay);
        az = fmaf(T, m.z, az);
        aw = fmaf(T, m.w, aw);
    }
    float4 r; r.x = ax; r.y = ay; r.z = az; r.w = aw;
    out4[b] = r;
}

extern "C" void kernel_launch(void* const* d_in, const int* in_sizes, int n_in,
                              void* d_out, int out_size, void* d_ws, size_t ws_size,
                              hipStream_t stream)
{
    const float* x      = (const float*)d_in[0];
    const float* params = (const float*)d_in[1];
    float*       out    = (float*)d_out;
    float4*      C4     = (float4*)d_ws;   // 81 float4 = 1296 B

    qc_setup<<<1, 256, 0, stream>>>(params, C4);

    const int batch = in_sizes[0] / 64;            // 131072
    qc_main<<<batch / 256, 256, 0, stream>>>(
        (const float4*)x, (const float4*)C4, (float4*)out);
}

// Round 5
// 79.530 us; speedup vs baseline: 1.0667x; 1.0667x over previous
//
#include <hip/hip_runtime.h>
#include <hip/hip_bf16.h>

// Quantum circuit: 4 qubits, batch 131072.  SINGLE fused kernel.
//
// angles[b][q] = sum_{g<16} x[b][g*4+q]        (RY fusion; RY(a)RY(b)=RY(a+b))
// psi = kron_q [cos(a_q/2), sin(a_q/2)]        (REAL product state)
// out[b][q] = <psi| U^dag Z_q U |psi>,  U = fixed 2-layer unitary(params).
//
// Pauli-basis reduction: for a real product state, <Y-containing strings> = 0,
// <I>=1, <X_q>=sin a_q, <Z_q>=cos a_q.  Hence
//     out_q = sum_{t in 3^4} C_q[t] * prod_q f_q(t_q),  f_q in {1, cos a_q, sin a_q}.
//
// The 4x81 coefficient table C depends only on params (24 floats); each block
// rebuilds it in LDS (~0.5us, amortized over 256 elements) -- this removes the
// separate 1-block setup dispatch that serialized in front of the main kernel.

__global__ __launch_bounds__(256) void qc_fused(const float4* __restrict__ x4,
                                                const float*  __restrict__ params,
                                                float4*       __restrict__ out4)
{
    __shared__ float  Ur[16][16];   // [k][col]
    __shared__ float  Ui[16][16];
    __shared__ float4 Mlds[256];    // M_q[i][j], q in lanes (not doubled)
    __shared__ float4 Clds[81];     // C_q[t]
    const int tid = threadIdx.x;

    // --- phase A1: threads 0..15 each simulate one basis column of U ---
    if (tid < 16) {
        const int col = tid;
        float ur[16], ui[16];
        #pragma unroll
        for (int k = 0; k < 16; ++k) { ur[k] = (k == col) ? 1.f : 0.f; ui[k] = 0.f; }

        #pragma unroll
        for (int l = 0; l < 2; ++l) {
            #pragma unroll
            for (int q = 0; q < 4; ++q) {
                const float phi = params[l*12 + q*3 + 0];
                const float th  = params[l*12 + q*3 + 1];
                const float om  = params[l*12 + q*3 + 2];
                float st, ct, sap, cap, sam, cam;
                __sincosf(0.5f*th,        &st,  &ct);
                __sincosf(0.5f*(phi+om),  &sap, &cap);
                __sincosf(0.5f*(phi-om),  &sam, &cam);
                // U00 = ct e^{-i ap}; U01 = -st e^{+i am}; U10 = st e^{-i am}; U11 = ct e^{+i ap}
                const float u00r =  ct*cap, u00i = -ct*sap;
                const float u01r = -st*cam, u01i = -st*sam;
                const float u10r =  st*cam, u10i = -st*sam;
                const float u11r =  ct*cap, u11i =  ct*sap;
                const int bit = 1 << (3 - q);
                #pragma unroll
                for (int k = 0; k < 16; ++k) {
                    if (k & bit) continue;
                    const int k1 = k | bit;
                    const float arr = ur[k],  aii = ui[k];
                    const float brr = ur[k1], bii = ui[k1];
                    ur[k]  = u00r*arr - u00i*aii + u01r*brr - u01i*bii;
                    ui[k]  = u00r*aii + u00i*arr + u01r*bii + u01i*brr;
                    ur[k1] = u10r*arr - u10i*aii + u11r*brr - u11i*bii;
                    ui[k1] = u10r*aii + u10i*arr + u11r*bii + u11i*brr;
                }
            }
            // CNOT ring (0,1),(1,2),(2,3),(3,0); qubit q lives in bit (3-q)
            const int cs[4] = {0,1,2,3}, ts[4] = {1,2,3,0};
            #pragma unroll
            for (int e = 0; e < 4; ++e) {
                const int cb = 3 - cs[e], tb = 3 - ts[e];
                float nr[16], ni[16];
                #pragma unroll
                for (int k = 0; k < 16; ++k) {
                    const int src = ((k >> cb) & 1) ? (k ^ (1 << tb)) : k;
                    nr[k] = ur[src]; ni[k] = ui[src];
                }
                #pragma unroll
                for (int k = 0; k < 16; ++k) { ur[k] = nr[k]; ui[k] = ni[k]; }
            }
        }
        #pragma unroll
        for (int k = 0; k < 16; ++k) { Ur[k][col] = ur[k]; Ui[k][col] = ui[k]; }
    }
    __syncthreads();

    // --- phase A2: thread (i,j) computes M_q[i][j] = sum_k z_q(k)(Ur[k][i]Ur[k][j]+Ui..) ---
    {
        const int i = tid >> 4, j = tid & 15;
        float m0 = 0.f, m1 = 0.f, m2 = 0.f, m3 = 0.f;
        #pragma unroll
        for (int k = 0; k < 16; ++k) {
            const float dot = Ur[k][i]*Ur[k][j] + Ui[k][i]*Ui[k][j];
            m0 += ((k >> 3) & 1) ? -dot : dot;
            m1 += ((k >> 2) & 1) ? -dot : dot;
            m2 += ((k >> 1) & 1) ? -dot : dot;
            m3 += ( k       & 1) ? -dot : dot;
        }
        float4 o; o.x = m0; o.y = m1; o.z = m2; o.w = m3;
        Mlds[tid] = o;
    }
    __syncthreads();

    // --- phase A3: threads 0..80 gather monomial coefficients ---
    // t = d0 + 3*d1 + 9*d2 + 27*d3, d_q in {0:I, 1:cos(Z), 2:sin(X)}.
    if (tid < 81) {
        int d[4]; int tt = tid;
        d[0] = tt % 3; tt /= 3; d[1] = tt % 3; tt /= 3; d[2] = tt % 3; d[3] = tt / 3;
        float ax = 0.f, ay = 0.f, az = 0.f, aw = 0.f;
        #pragma unroll
        for (int combo = 0; combo < 16; ++combo) {
            int i = 0, j = 0; float w = 1.f;
            #pragma unroll
            for (int q = 0; q < 4; ++q) {
                const int o = (combo >> q) & 1;
                int bi, bj; float wq;
                if (d[q] == 2)      { bi = o; bj = 1 - o; wq = 0.5f; }
                else if (d[q] == 1) { bi = o; bj = o;     wq = o ? -0.5f : 0.5f; }
                else                { bi = o; bj = o;     wq = 0.5f; }
                i |= bi << (3 - q); j |= bj << (3 - q);
                w *= wq;
            }
            const float4 m = Mlds[i*16 + j];
            ax = fmaf(w, m.x, ax);
            ay = fmaf(w, m.y, ay);
            az = fmaf(w, m.z, az);
            aw = fmaf(w, m.w, aw);
        }
        float4 c; c.x = ax; c.y = ay; c.z = az; c.w = aw;
        Clds[tid] = c;
    }
    __syncthreads();

    // --- phase B: per-element evaluation (memory-bound: 256B in, 16B out per elem) ---
    const int b = blockIdx.x * 256 + tid;
    const float4* row = x4 + ((size_t)b << 4);

    float a0 = 0.f, a1 = 0.f, a2 = 0.f, a3 = 0.f;
    #pragma unroll
    for (int j = 0; j < 16; ++j) {
        const float4 v = row[j];
        a0 += v.x; a1 += v.y; a2 += v.z; a3 += v.w;
    }

    float c0,s0,c1,s1,c2,s2,c3,s3;
    __sincosf(a0, &s0, &c0);
    __sincosf(a1, &s1, &c1);
    __sincosf(a2, &s2, &c2);
    __sincosf(a3, &s3, &c3);

    const float g0[3] = {1.f, c0, s0};
    const float g1[3] = {1.f, c1, s1};
    const float g2[3] = {1.f, c2, s2};
    const float g3[3] = {1.f, c3, s3};
    float P01[9], P23[9];
    #pragma unroll
    for (int e1 = 0; e1 < 3; ++e1)
        #pragma unroll
        for (int e0 = 0; e0 < 3; ++e0) {
            P01[e0 + 3*e1] = g0[e0] * g1[e1];
            P23[e0 + 3*e1] = g2[e0] * g3[e1];
        }

    // out_q = sum_t C_q[t] * P01[t%9] * P23[t/9]; uniform-addr LDS broadcast reads
    float ax = 0.f, ay = 0.f, az = 0.f, aw = 0.f;
    #pragma unroll
    for (int t = 0; t < 81; ++t) {
        const float T = P01[t % 9] * P23[t / 9];
        const float4 m = Clds[t];
        ax = fmaf(T, m.x, ax);
        ay = fmaf(T, m.y, ay);
        az = fmaf(T, m.z, az);
        aw = fmaf(T, m.w, aw);
    }
    float4 r; r.x = ax; r.y = ay; r.z = az; r.w = aw;
    out4[b] = r;
}

extern "C" void kernel_launch(void* const* d_in, const int* in_sizes, int n_in,
                              void* d_out, int out_size, void* d_ws, size_t ws_size,
                              hipStream_t stream)
{
    const float* x      = (const float*)d_in[0];
    const float* params = (const float*)d_in[1];
    float*       out    = (float*)d_out;
    (void)d_ws; (void)ws_size;

    const int batch = in_sizes[0] / 64;            // 131072
    qc_fused<<<batch / 256, 256, 0, stream>>>(
        (const float4*)x, params, (float4*)out);
}